// Round 1
// baseline (849.646 us; speedup 1.0000x reference)
//
#include <hip/hip_runtime.h>
#include <cmath>

static constexpr int NN  = 50000;   // nodes
static constexpr int NE  = 800000;  // edges
static constexpr int HID = 64;
static constexpr int BB  = 64;      // batch
static constexpr int TT  = 200;     // seq len
static constexpr int LH  = 128;     // lstm hidden
static constexpr int G4  = 512;     // 4*LH

__device__ __forceinline__ float sigmoidf_(float x) { return 1.f / (1.f + __expf(-x)); }

// ---------------- edge pass: e = EA @ W^T + b; m = relu(h[src]+e); agg[dst] += m ----------------
__global__ __launch_bounds__(256) void edge_kernel(
    const float* __restrict__ h_in,
    const float* __restrict__ ea,
    const float* __restrict__ W,     // [64][64] row-major W[c][k]
    const float* __restrict__ bias,  // [64]
    const int*   __restrict__ srcs,
    const int*   __restrict__ dsts,
    float*       __restrict__ agg)
{
    __shared__ float4 stage[4][64];  // per wave: 4 edges x 64 ch
    const int lane = threadIdx.x & 63;
    const int wid  = threadIdx.x >> 6;

    // weight row 'lane' in registers
    float w[64];
    {
        const float4* wf = (const float4*)(W + lane * 64);
        #pragma unroll
        for (int k4 = 0; k4 < 16; ++k4) {
            float4 v = wf[k4];
            w[4*k4+0] = v.x; w[4*k4+1] = v.y; w[4*k4+2] = v.z; w[4*k4+3] = v.w;
        }
    }
    const float bc = bias[lane];
    const float4* eaf = (const float4*)ea;

    const int gw = blockIdx.x * 4 + wid;     // global wave id
    const int nw = gridDim.x * 4;
    for (int e0 = gw * 4; e0 < NE; e0 += nw * 4) {
        // stage 4 edges (1 KB) coalesced
        stage[wid][lane] = eaf[(size_t)e0 * 16 + lane];
        asm volatile("s_waitcnt lgkmcnt(0)" ::: "memory");
        const float4* st = &stage[wid][0];
        #pragma unroll
        for (int j = 0; j < 4; ++j) {
            const int e = e0 + j;
            const int s = srcs[e];
            const int d = dsts[e];
            float acc = bc;
            #pragma unroll
            for (int k4 = 0; k4 < 16; ++k4) {
                float4 v = st[j*16 + k4];   // broadcast read
                acc = fmaf(v.x, w[4*k4+0], acc);
                acc = fmaf(v.y, w[4*k4+1], acc);
                acc = fmaf(v.z, w[4*k4+2], acc);
                acc = fmaf(v.w, w[4*k4+3], acc);
            }
            float m = acc + h_in[(size_t)s * HID + lane];
            m = m > 0.f ? m : 0.f;
            unsafeAtomicAdd(&agg[(size_t)d * HID + lane], m);
        }
    }
}

// ---------------- node pass: z=(1+eps)h+agg; z=relu(z@W1^T+b1)@W2^T+b2; LN; relu ----------------
__global__ __launch_bounds__(256) void node_kernel(
    const float* __restrict__ h_in,
    const float* __restrict__ agg,
    const float* __restrict__ W1, const float* __restrict__ b1,
    const float* __restrict__ W2, const float* __restrict__ b2,
    const float* __restrict__ epsp,
    const float* __restrict__ lnS, const float* __restrict__ lnB,
    float*       __restrict__ h_out)
{
    __shared__ float zbuf[4][64];
    __shared__ float tbuf[4][64];
    const int lane = threadIdx.x & 63;
    const int wid  = threadIdx.x >> 6;

    float w1[64], w2[64];
    {
        const float4* wf1 = (const float4*)(W1 + lane * 64);
        const float4* wf2 = (const float4*)(W2 + lane * 64);
        #pragma unroll
        for (int k4 = 0; k4 < 16; ++k4) {
            float4 a = wf1[k4], b = wf2[k4];
            w1[4*k4+0]=a.x; w1[4*k4+1]=a.y; w1[4*k4+2]=a.z; w1[4*k4+3]=a.w;
            w2[4*k4+0]=b.x; w2[4*k4+1]=b.y; w2[4*k4+2]=b.z; w2[4*k4+3]=b.w;
        }
    }
    const float b1c = b1[lane], b2c = b2[lane];
    const float sC = lnS[lane], bC = lnB[lane];
    const float epv = 1.f + epsp[0];

    const int gw = blockIdx.x * 4 + wid;
    const int nw = gridDim.x * 4;
    for (int n = gw; n < NN; n += nw) {
        float z = epv * h_in[(size_t)n*HID + lane] + agg[(size_t)n*HID + lane];
        zbuf[wid][lane] = z;
        asm volatile("s_waitcnt lgkmcnt(0)" ::: "memory");
        float acc = b1c;
        {
            const float4* zf = (const float4*)&zbuf[wid][0];
            #pragma unroll
            for (int k4 = 0; k4 < 16; ++k4) {
                float4 v = zf[k4];
                acc = fmaf(v.x, w1[4*k4+0], acc);
                acc = fmaf(v.y, w1[4*k4+1], acc);
                acc = fmaf(v.z, w1[4*k4+2], acc);
                acc = fmaf(v.w, w1[4*k4+3], acc);
            }
        }
        acc = acc > 0.f ? acc : 0.f;
        tbuf[wid][lane] = acc;
        asm volatile("s_waitcnt lgkmcnt(0)" ::: "memory");
        float acc2 = b2c;
        {
            const float4* tf = (const float4*)&tbuf[wid][0];
            #pragma unroll
            for (int k4 = 0; k4 < 16; ++k4) {
                float4 v = tf[k4];
                acc2 = fmaf(v.x, w2[4*k4+0], acc2);
                acc2 = fmaf(v.y, w2[4*k4+1], acc2);
                acc2 = fmaf(v.z, w2[4*k4+2], acc2);
                acc2 = fmaf(v.w, w2[4*k4+3], acc2);
            }
        }
        // layernorm across the 64 lanes
        float s1 = acc2, s2 = acc2 * acc2;
        #pragma unroll
        for (int off = 32; off >= 1; off >>= 1) {
            s1 += __shfl_xor(s1, off);
            s2 += __shfl_xor(s2, off);
        }
        float mu  = s1 * (1.f/64.f);
        float var = s2 * (1.f/64.f) - mu * mu;
        float r   = rsqrtf(var + 1e-5f);
        float o   = (acc2 - mu) * r * sC + bC;
        h_out[(size_t)n*HID + lane] = o > 0.f ? o : 0.f;
    }
}

// ---------------- prep: W2T transpose + selp = b_ih + sel @ W_ih[:, :64]^T ----------------
__global__ __launch_bounds__(512) void prep_kernel(
    const float* __restrict__ Wih,   // [512][96]
    const float* __restrict__ bih,   // [512]
    const float* __restrict__ h2,    // [NN][64]
    const int*   __restrict__ nidx,  // [64]
    float*       __restrict__ W2T,   // [32][512]
    float*       __restrict__ selp)  // [64][512]
{
    const int g = threadIdx.x;
    if (blockIdx.x == BB) {
        #pragma unroll
        for (int k = 0; k < 32; ++k)
            W2T[k * G4 + g] = Wih[g * 96 + 64 + k];
    } else {
        const int b = blockIdx.x;
        __shared__ float hrow[64];
        if (g < 64) hrow[g] = h2[(size_t)nidx[b] * HID + g];
        __syncthreads();
        float acc = bih[g];
        #pragma unroll
        for (int k = 0; k < 64; ++k)
            acc = fmaf(hrow[k], Wih[g * 96 + k], acc);
        selp[b * G4 + g] = acc;
    }
}

// ---------------- xp[t][b][g] = selp[b][g] + x_seq[b][t] @ W2T[:,g] ----------------
__global__ __launch_bounds__(512) void xp_kernel(
    const float* __restrict__ xseq,  // [B][T][32]
    const float* __restrict__ selp,  // [B][512]
    const float* __restrict__ W2T,   // [32][512]
    float*       __restrict__ xp)    // [T][B][512]
{
    const int g   = threadIdx.x;
    const int row = blockIdx.x;      // row = t*64 + b
    const int t   = row >> 6;
    const int b   = row & 63;
    __shared__ float xs[32];
    if (g < 32) xs[g] = xseq[((size_t)b * TT + t) * 32 + g];
    __syncthreads();
    float acc = selp[b * G4 + g];
    #pragma unroll
    for (int k = 0; k < 32; ++k)
        acc = fmaf(xs[k], W2T[k * G4 + g], acc);
    xp[(size_t)row * G4 + g] = acc;
}

// ---------------- LSTM recurrence + final LN + fc ----------------
__global__ __launch_bounds__(512) void lstm_kernel(
    const float* __restrict__ xp,    // [T][B][512]
    const float* __restrict__ Whh,   // [512][128]
    const float* __restrict__ bhh,   // [512]
    const float* __restrict__ lnS, const float* __restrict__ lnB,  // [128]
    const float* __restrict__ fcW,   // [1][128]
    const float* __restrict__ fcb,   // [1]
    float*       __restrict__ out)   // [64]
{
    const int g = threadIdx.x;   // gate index 0..511
    const int b = blockIdx.x;    // batch row

    float w[128];
    {
        const float4* wf = (const float4*)(Whh + (size_t)g * LH);
        #pragma unroll
        for (int k4 = 0; k4 < 32; ++k4) {
            float4 v = wf[k4];
            w[4*k4+0]=v.x; w[4*k4+1]=v.y; w[4*k4+2]=v.z; w[4*k4+3]=v.w;
        }
    }
    const float bg = bhh[g];

    __shared__ float h_lds[LH];
    __shared__ float gates[G4];
    if (g < LH) h_lds[g] = 0.f;
    float c = 0.f;
    __syncthreads();

    for (int t = 0; t < TT; ++t) {
        float a0 = 0.f, a1 = 0.f, a2 = 0.f, a3 = 0.f;
        const float4* h4 = (const float4*)h_lds;
        #pragma unroll
        for (int k4 = 0; k4 < 32; k4 += 4) {
            float4 v0 = h4[k4+0], v1 = h4[k4+1], v2 = h4[k4+2], v3 = h4[k4+3];
            a0 = fmaf(v0.x, w[4*k4+ 0], a0); a0 = fmaf(v0.y, w[4*k4+ 1], a0);
            a0 = fmaf(v0.z, w[4*k4+ 2], a0); a0 = fmaf(v0.w, w[4*k4+ 3], a0);
            a1 = fmaf(v1.x, w[4*k4+ 4], a1); a1 = fmaf(v1.y, w[4*k4+ 5], a1);
            a1 = fmaf(v1.z, w[4*k4+ 6], a1); a1 = fmaf(v1.w, w[4*k4+ 7], a1);
            a2 = fmaf(v2.x, w[4*k4+ 8], a2); a2 = fmaf(v2.y, w[4*k4+ 9], a2);
            a2 = fmaf(v2.z, w[4*k4+10], a2); a2 = fmaf(v2.w, w[4*k4+11], a2);
            a3 = fmaf(v3.x, w[4*k4+12], a3); a3 = fmaf(v3.y, w[4*k4+13], a3);
            a3 = fmaf(v3.z, w[4*k4+14], a3); a3 = fmaf(v3.w, w[4*k4+15], a3);
        }
        float acc = xp[((size_t)t * BB + b) * G4 + g] + bg + ((a0 + a1) + (a2 + a3));
        __syncthreads();           // protect h_lds until all dots done
        gates[g] = acc;
        __syncthreads();
        if (g < LH) {
            float iv = sigmoidf_(gates[g]);
            float fv = sigmoidf_(gates[g + LH]);
            float gv = tanhf(gates[g + 2*LH]);
            float ov = sigmoidf_(gates[g + 3*LH]);
            c = fv * c + iv * gv;
            h_lds[g] = ov * tanhf(c);
        }
        __syncthreads();
    }

    // epilogue: layernorm over h (128) + fc -> out[b]
    if (g < 64) {
        float h0 = h_lds[g], h1 = h_lds[g + 64];
        float s1 = h0 + h1, s2 = h0*h0 + h1*h1;
        #pragma unroll
        for (int off = 32; off >= 1; off >>= 1) {
            s1 += __shfl_xor(s1, off);
            s2 += __shfl_xor(s2, off);
        }
        float mu  = s1 * (1.f/128.f);
        float var = s2 * (1.f/128.f) - mu * mu;
        float r   = rsqrtf(var + 1e-5f);
        float p = ((h0 - mu)*r*lnS[g]      + lnB[g])      * fcW[g]
                + ((h1 - mu)*r*lnS[g + 64] + lnB[g + 64]) * fcW[g + 64];
        #pragma unroll
        for (int off = 32; off >= 1; off >>= 1) p += __shfl_xor(p, off);
        if (g == 0) out[b] = p + fcb[0];
    }
}

extern "C" void kernel_launch(void* const* d_in, const int* in_sizes, int n_in,
                              void* d_out, int out_size, void* d_ws, size_t ws_size,
                              hipStream_t stream) {
    const float* x     = (const float*)d_in[0];
    const float* ea    = (const float*)d_in[1];
    const float* xseq  = (const float*)d_in[2];
    const float* linW  = (const float*)d_in[3];
    const float* linB  = (const float*)d_in[4];
    const float* mW1   = (const float*)d_in[5];
    const float* mb1   = (const float*)d_in[6];
    const float* mW2   = (const float*)d_in[7];
    const float* mb2   = (const float*)d_in[8];
    const float* eps   = (const float*)d_in[9];
    const float* lnS   = (const float*)d_in[10];
    const float* lnB   = (const float*)d_in[11];
    const float* Wih   = (const float*)d_in[12];
    const float* Whh   = (const float*)d_in[13];
    const float* bih   = (const float*)d_in[14];
    const float* bhh   = (const float*)d_in[15];
    const float* llnS  = (const float*)d_in[16];
    const float* llnB  = (const float*)d_in[17];
    const float* fcW   = (const float*)d_in[18];
    const float* fcb   = (const float*)d_in[19];
    const int*   eidx  = (const int*)d_in[20];
    const int*   nidx  = (const int*)d_in[21];
    float* out = (float*)d_out;

    const int* srcs = eidx;
    const int* dsts = eidx + NE;

    // workspace layout (floats)
    float* ws   = (float*)d_ws;
    float* agg  = ws;                          // 3.2M
    float* h1   = agg  + (size_t)NN * HID;     // 3.2M
    float* h2   = h1   + (size_t)NN * HID;     // 3.2M
    float* selp = h2   + (size_t)NN * HID;     // 32768
    float* W2T  = selp + (size_t)BB * G4;      // 16384
    float* xp   = W2T  + (size_t)32 * G4;      // 6.5536M

    const size_t aggBytes = (size_t)NN * HID * sizeof(float);

    // ---- layer 0 ----
    hipMemsetAsync(agg, 0, aggBytes, stream);
    edge_kernel<<<2048, 256, 0, stream>>>(x, ea, linW, linB, srcs, dsts, agg);
    node_kernel<<<512, 256, 0, stream>>>(x, agg, mW1, mb1, mW2, mb2, eps, lnS, lnB, h1);
    // ---- layer 1 ----
    hipMemsetAsync(agg, 0, aggBytes, stream);
    edge_kernel<<<2048, 256, 0, stream>>>(h1, ea, linW + 64*64, linB + 64, srcs, dsts, agg);
    node_kernel<<<512, 256, 0, stream>>>(h1, agg, mW1 + 64*64, mb1 + 64, mW2 + 64*64, mb2 + 64,
                                         eps + 1, lnS + 64, lnB + 64, h2);
    // ---- LSTM input projection ----
    prep_kernel<<<BB + 1, 512, 0, stream>>>(Wih, bih, h2, nidx, W2T, selp);
    xp_kernel<<<TT * BB, 512, 0, stream>>>(xseq, selp, W2T, xp);
    // ---- LSTM recurrence + head ----
    lstm_kernel<<<BB, 512, 0, stream>>>(xp, Whh, bhh, llnS, llnB, fcW, fcb, out);
}

// Round 2
// 703.786 us; speedup vs baseline: 1.2072x; 1.2072x over previous
//
#include <hip/hip_runtime.h>
#include <cmath>

static constexpr int NN  = 50000;   // nodes
static constexpr int NE  = 800000;  // edges
static constexpr int HID = 64;
static constexpr int BB  = 64;      // batch
static constexpr int TT  = 200;     // seq len
static constexpr int LH  = 128;     // lstm hidden
static constexpr int G4  = 512;     // 4*LH

__device__ __forceinline__ float sigmoid_fast(float x) {
    return __fdividef(1.f, 1.f + __expf(-x));
}
__device__ __forceinline__ float tanh_fast(float x) {
    // 2*sigmoid(2x)-1 ; no overflow: exp(-2x)->inf gives -1, ->0 gives +1
    return __fdividef(2.f, 1.f + __expf(-2.f * x)) - 1.f;
}

// ---------------- edge pass: e = EA @ W^T + b; m = relu(h[src]+e); agg[dst] += m ----------------
__global__ __launch_bounds__(256) void edge_kernel(
    const float* __restrict__ h_in,
    const float* __restrict__ ea,
    const float* __restrict__ W,     // [64][64] row-major W[c][k]
    const float* __restrict__ bias,  // [64]
    const int*   __restrict__ srcs,
    const int*   __restrict__ dsts,
    float*       __restrict__ agg)
{
    __shared__ float4 stage[4][64];  // per wave: 4 edges x 64 ch
    const int lane = threadIdx.x & 63;
    const int wid  = threadIdx.x >> 6;

    float w[64];
    {
        const float4* wf = (const float4*)(W + lane * 64);
        #pragma unroll
        for (int k4 = 0; k4 < 16; ++k4) {
            float4 v = wf[k4];
            w[4*k4+0] = v.x; w[4*k4+1] = v.y; w[4*k4+2] = v.z; w[4*k4+3] = v.w;
        }
    }
    const float bc = bias[lane];
    const float4* eaf = (const float4*)ea;

    const int gw = blockIdx.x * 4 + wid;     // global wave id
    const int nw = gridDim.x * 4;
    for (int e0 = gw * 4; e0 < NE; e0 += nw * 4) {
        stage[wid][lane] = eaf[(size_t)e0 * 16 + lane];
        asm volatile("s_waitcnt lgkmcnt(0)" ::: "memory");
        const float4* st = &stage[wid][0];
        #pragma unroll
        for (int j = 0; j < 4; ++j) {
            const int e = e0 + j;
            const int s = srcs[e];
            const int d = dsts[e];
            float acc = bc;
            #pragma unroll
            for (int k4 = 0; k4 < 16; ++k4) {
                float4 v = st[j*16 + k4];   // broadcast read
                acc = fmaf(v.x, w[4*k4+0], acc);
                acc = fmaf(v.y, w[4*k4+1], acc);
                acc = fmaf(v.z, w[4*k4+2], acc);
                acc = fmaf(v.w, w[4*k4+3], acc);
            }
            float m = acc + h_in[(size_t)s * HID + lane];
            m = m > 0.f ? m : 0.f;
            unsafeAtomicAdd(&agg[(size_t)d * HID + lane], m);
        }
    }
}

// ---------------- node pass: z=(1+eps)h+agg; z=relu(z@W1^T+b1)@W2^T+b2; LN; relu ----------------
__global__ __launch_bounds__(256) void node_kernel(
    const float* __restrict__ h_in,
    const float* __restrict__ agg,
    const float* __restrict__ W1, const float* __restrict__ b1,
    const float* __restrict__ W2, const float* __restrict__ b2,
    const float* __restrict__ epsp,
    const float* __restrict__ lnS, const float* __restrict__ lnB,
    float*       __restrict__ h_out)
{
    __shared__ float zbuf[4][64];
    __shared__ float tbuf[4][64];
    const int lane = threadIdx.x & 63;
    const int wid  = threadIdx.x >> 6;

    float w1[64], w2[64];
    {
        const float4* wf1 = (const float4*)(W1 + lane * 64);
        const float4* wf2 = (const float4*)(W2 + lane * 64);
        #pragma unroll
        for (int k4 = 0; k4 < 16; ++k4) {
            float4 a = wf1[k4], b = wf2[k4];
            w1[4*k4+0]=a.x; w1[4*k4+1]=a.y; w1[4*k4+2]=a.z; w1[4*k4+3]=a.w;
            w2[4*k4+0]=b.x; w2[4*k4+1]=b.y; w2[4*k4+2]=b.z; w2[4*k4+3]=b.w;
        }
    }
    const float b1c = b1[lane], b2c = b2[lane];
    const float sC = lnS[lane], bC = lnB[lane];
    const float epv = 1.f + epsp[0];

    const int gw = blockIdx.x * 4 + wid;
    const int nw = gridDim.x * 4;
    for (int n = gw; n < NN; n += nw) {
        float z = epv * h_in[(size_t)n*HID + lane] + agg[(size_t)n*HID + lane];
        zbuf[wid][lane] = z;
        asm volatile("s_waitcnt lgkmcnt(0)" ::: "memory");
        float acc = b1c;
        {
            const float4* zf = (const float4*)&zbuf[wid][0];
            #pragma unroll
            for (int k4 = 0; k4 < 16; ++k4) {
                float4 v = zf[k4];
                acc = fmaf(v.x, w1[4*k4+0], acc);
                acc = fmaf(v.y, w1[4*k4+1], acc);
                acc = fmaf(v.z, w1[4*k4+2], acc);
                acc = fmaf(v.w, w1[4*k4+3], acc);
            }
        }
        acc = acc > 0.f ? acc : 0.f;
        tbuf[wid][lane] = acc;
        asm volatile("s_waitcnt lgkmcnt(0)" ::: "memory");
        float acc2 = b2c;
        {
            const float4* tf = (const float4*)&tbuf[wid][0];
            #pragma unroll
            for (int k4 = 0; k4 < 16; ++k4) {
                float4 v = tf[k4];
                acc2 = fmaf(v.x, w2[4*k4+0], acc2);
                acc2 = fmaf(v.y, w2[4*k4+1], acc2);
                acc2 = fmaf(v.z, w2[4*k4+2], acc2);
                acc2 = fmaf(v.w, w2[4*k4+3], acc2);
            }
        }
        float s1 = acc2, s2 = acc2 * acc2;
        #pragma unroll
        for (int off = 32; off >= 1; off >>= 1) {
            s1 += __shfl_xor(s1, off);
            s2 += __shfl_xor(s2, off);
        }
        float mu  = s1 * (1.f/64.f);
        float var = s2 * (1.f/64.f) - mu * mu;
        float r   = rsqrtf(var + 1e-5f);
        float o   = (acc2 - mu) * r * sC + bC;
        h_out[(size_t)n*HID + lane] = o > 0.f ? o : 0.f;
    }
}

// ---------------- prep: W2T transpose + selp = b_ih + sel @ W_ih[:, :64]^T ----------------
__global__ __launch_bounds__(512) void prep_kernel(
    const float* __restrict__ Wih,   // [512][96]
    const float* __restrict__ bih,   // [512]
    const float* __restrict__ h2,    // [NN][64]
    const int*   __restrict__ nidx,  // [64]
    float*       __restrict__ W2T,   // [32][512]
    float*       __restrict__ selp)  // [64][512]
{
    const int g = threadIdx.x;
    if (blockIdx.x == BB) {
        #pragma unroll
        for (int k = 0; k < 32; ++k)
            W2T[k * G4 + g] = Wih[g * 96 + 64 + k];
    } else {
        const int b = blockIdx.x;
        __shared__ float hrow[64];
        if (g < 64) hrow[g] = h2[(size_t)nidx[b] * HID + g];
        __syncthreads();
        float acc = bih[g];
        #pragma unroll
        for (int k = 0; k < 64; ++k)
            acc = fmaf(hrow[k], Wih[g * 96 + k], acc);
        selp[b * G4 + g] = acc;
    }
}

// ---------------- xp[t][b][g] = selp[b][g] + x_seq[b][t] @ W2T[:,g] ----------------
__global__ __launch_bounds__(512) void xp_kernel(
    const float* __restrict__ xseq,  // [B][T][32]
    const float* __restrict__ selp,  // [B][512]
    const float* __restrict__ W2T,   // [32][512]
    float*       __restrict__ xp)    // [T][B][512]
{
    const int g   = threadIdx.x;
    const int row = blockIdx.x;      // row = t*64 + b
    const int t   = row >> 6;
    const int b   = row & 63;
    __shared__ float xs[32];
    if (g < 32) xs[g] = xseq[((size_t)b * TT + t) * 32 + g];
    __syncthreads();
    float acc = selp[b * G4 + g];
    #pragma unroll
    for (int k = 0; k < 32; ++k)
        acc = fmaf(xs[k], W2T[k * G4 + g], acc);
    xp[(size_t)row * G4 + g] = acc;
}

// ---------------- LSTM recurrence + final LN + fc ----------------
// 64 blocks (one per batch row) x 512 threads (one per gate row).
// 2 barriers/step; activations applied in producer threads (wave-uniform);
// c replicated x4 so the elementwise phase runs in all 8 waves; xp prefetched.
__global__ __launch_bounds__(512) void lstm_kernel(
    const float* __restrict__ xp,    // [T][B][512]
    const float* __restrict__ Whh,   // [512][128]
    const float* __restrict__ bhh,   // [512]
    const float* __restrict__ lnS, const float* __restrict__ lnB,  // [128]
    const float* __restrict__ fcW,   // [1][128]
    const float* __restrict__ fcb,   // [1]
    float*       __restrict__ out)   // [64]
{
    const int g = threadIdx.x;   // gate index 0..511
    const int b = blockIdx.x;    // batch row
    const int j = g & 127;       // hidden unit this thread's elementwise phase owns
    const int gt = g >> 7;       // gate type: 0=i 1=f 2=g 3=o (wave-uniform)

    float w[128];
    {
        const float4* wf = (const float4*)(Whh + (size_t)g * LH);
        #pragma unroll
        for (int k4 = 0; k4 < 32; ++k4) {
            float4 v = wf[k4];
            w[4*k4+0]=v.x; w[4*k4+1]=v.y; w[4*k4+2]=v.z; w[4*k4+3]=v.w;
        }
    }
    const float bg = bhh[g];

    __shared__ float h_lds[LH];
    __shared__ float gates[G4];
    if (g < LH) h_lds[g] = 0.f;
    float c = 0.f;               // replicated per hidden unit j across 4 threads
    __syncthreads();

    float xv = xp[(size_t)b * G4 + g];   // t=0 slice

    for (int t = 0; t < TT; ++t) {
        // prefetch next timestep's xp early; arrives during the dot loop
        const int tn = (t + 1 < TT) ? t + 1 : t;
        const float xv_next = xp[((size_t)tn * BB + b) * G4 + g];

        float a0 = 0.f, a1 = 0.f, a2 = 0.f, a3 = 0.f;
        const float4* h4 = (const float4*)h_lds;
        #pragma unroll
        for (int k4 = 0; k4 < 32; k4 += 4) {
            float4 v0 = h4[k4+0], v1 = h4[k4+1], v2 = h4[k4+2], v3 = h4[k4+3];
            a0 = fmaf(v0.x, w[4*k4+ 0], a0); a0 = fmaf(v0.y, w[4*k4+ 1], a0);
            a0 = fmaf(v0.z, w[4*k4+ 2], a0); a0 = fmaf(v0.w, w[4*k4+ 3], a0);
            a1 = fmaf(v1.x, w[4*k4+ 4], a1); a1 = fmaf(v1.y, w[4*k4+ 5], a1);
            a1 = fmaf(v1.z, w[4*k4+ 6], a1); a1 = fmaf(v1.w, w[4*k4+ 7], a1);
            a2 = fmaf(v2.x, w[4*k4+ 8], a2); a2 = fmaf(v2.y, w[4*k4+ 9], a2);
            a2 = fmaf(v2.z, w[4*k4+10], a2); a2 = fmaf(v2.w, w[4*k4+11], a2);
            a3 = fmaf(v3.x, w[4*k4+12], a3); a3 = fmaf(v3.y, w[4*k4+13], a3);
            a3 = fmaf(v3.z, w[4*k4+14], a3); a3 = fmaf(v3.w, w[4*k4+15], a3);
        }
        float acc = xv + bg + ((a0 + a1) + (a2 + a3));

        // activation in producer thread (branch is wave-uniform: gt = g>>7)
        float act = (gt == 2) ? tanh_fast(acc) : sigmoid_fast(acc);
        gates[g] = act;
        __syncthreads();                       // gates visible; all h reads done

        // replicated elementwise update (all 8 waves)
        float iv = gates[j];
        float fv = gates[j + LH];
        float gv = gates[j + 2*LH];
        float ov = gates[j + 3*LH];
        c = fmaf(fv, c, iv * gv);
        float hv = ov * tanh_fast(c);
        if (g < LH) h_lds[j] = hv;
        __syncthreads();                       // h visible for next step

        xv = xv_next;
    }

    // epilogue: layernorm over h (128) + fc -> out[b]
    if (g < 64) {
        float h0 = h_lds[g], h1 = h_lds[g + 64];
        float s1 = h0 + h1, s2 = h0*h0 + h1*h1;
        #pragma unroll
        for (int off = 32; off >= 1; off >>= 1) {
            s1 += __shfl_xor(s1, off);
            s2 += __shfl_xor(s2, off);
        }
        float mu  = s1 * (1.f/128.f);
        float var = s2 * (1.f/128.f) - mu * mu;
        float r   = rsqrtf(var + 1e-5f);
        float p = ((h0 - mu)*r*lnS[g]      + lnB[g])      * fcW[g]
                + ((h1 - mu)*r*lnS[g + 64] + lnB[g + 64]) * fcW[g + 64];
        #pragma unroll
        for (int off = 32; off >= 1; off >>= 1) p += __shfl_xor(p, off);
        if (g == 0) out[b] = p + fcb[0];
    }
}

extern "C" void kernel_launch(void* const* d_in, const int* in_sizes, int n_in,
                              void* d_out, int out_size, void* d_ws, size_t ws_size,
                              hipStream_t stream) {
    const float* x     = (const float*)d_in[0];
    const float* ea    = (const float*)d_in[1];
    const float* xseq  = (const float*)d_in[2];
    const float* linW  = (const float*)d_in[3];
    const float* linB  = (const float*)d_in[4];
    const float* mW1   = (const float*)d_in[5];
    const float* mb1   = (const float*)d_in[6];
    const float* mW2   = (const float*)d_in[7];
    const float* mb2   = (const float*)d_in[8];
    const float* eps   = (const float*)d_in[9];
    const float* lnS   = (const float*)d_in[10];
    const float* lnB   = (const float*)d_in[11];
    const float* Wih   = (const float*)d_in[12];
    const float* Whh   = (const float*)d_in[13];
    const float* bih   = (const float*)d_in[14];
    const float* bhh   = (const float*)d_in[15];
    const float* llnS  = (const float*)d_in[16];
    const float* llnB  = (const float*)d_in[17];
    const float* fcW   = (const float*)d_in[18];
    const float* fcb   = (const float*)d_in[19];
    const int*   eidx  = (const int*)d_in[20];
    const int*   nidx  = (const int*)d_in[21];
    float* out = (float*)d_out;

    const int* srcs = eidx;
    const int* dsts = eidx + NE;

    // workspace layout (floats)
    float* ws   = (float*)d_ws;
    float* agg  = ws;                          // 3.2M
    float* h1   = agg  + (size_t)NN * HID;     // 3.2M
    float* h2   = h1   + (size_t)NN * HID;     // 3.2M
    float* selp = h2   + (size_t)NN * HID;     // 32768
    float* W2T  = selp + (size_t)BB * G4;      // 16384
    float* xp   = W2T  + (size_t)32 * G4;      // 6.5536M

    const size_t aggBytes = (size_t)NN * HID * sizeof(float);

    // ---- layer 0 ----
    hipMemsetAsync(agg, 0, aggBytes, stream);
    edge_kernel<<<2048, 256, 0, stream>>>(x, ea, linW, linB, srcs, dsts, agg);
    node_kernel<<<512, 256, 0, stream>>>(x, agg, mW1, mb1, mW2, mb2, eps, lnS, lnB, h1);
    // ---- layer 1 ----
    hipMemsetAsync(agg, 0, aggBytes, stream);
    edge_kernel<<<2048, 256, 0, stream>>>(h1, ea, linW + 64*64, linB + 64, srcs, dsts, agg);
    node_kernel<<<512, 256, 0, stream>>>(h1, agg, mW1 + 64*64, mb1 + 64, mW2 + 64*64, mb2 + 64,
                                         eps + 1, lnS + 64, lnB + 64, h2);
    // ---- LSTM input projection ----
    prep_kernel<<<BB + 1, 512, 0, stream>>>(Wih, bih, h2, nidx, W2T, selp);
    xp_kernel<<<TT * BB, 512, 0, stream>>>(xseq, selp, W2T, xp);
    // ---- LSTM recurrence + head ----
    lstm_kernel<<<BB, 512, 0, stream>>>(xp, Whh, bhh, llnS, llnB, fcW, fcb, out);
}